// Round 3
// baseline (180.852 us; speedup 1.0000x reference)
//
#include <hip/hip_runtime.h>

#define SDIM 4096
#define ALPHA 0.01f
#define WS_ARR 32                    // float offset: gathered column arrays
#define WS_PART (WS_ARR + 5 * SDIM)  // per-block partials (2 * 4096 floats)

// ws layout (floats):
//   [8..24)                       16 per-block log partials (k_gather)
//   [32 .. 32+5*4096)             c0 | c1 | c3 | t0 | t1  (gathered columns)
//   [WS_PART .. +4096)            per-row sum_sq partials (k_main)
//   [WS_PART+4096 .. +8192)       per-row sum3 partials   (k_main)

// ---------------------------------------------------------------------------
// Kernel 1: gather columns, compute log partials.
// grid = 16 blocks x 256 threads (one thread per row)
// ---------------------------------------------------------------------------
__global__ void k_gather(const float* __restrict__ inp, const float* __restrict__ tgt,
                         float* __restrict__ ws) {
    __shared__ float sbuf[4];
    int n = blockIdx.x * blockDim.x + threadIdx.x;  // 0..4095
    const float* row = inp + (size_t)n * SDIM;
    const float* trow = tgt + (size_t)n * SDIM;
    float* arr = ws + WS_ARR;

    float v0 = row[0], v1 = row[1], v3 = row[3], v4 = row[4];
    arr[n]            = v0;            // c0
    arr[SDIM + n]     = v1;            // c1
    arr[2 * SDIM + n] = v3;            // c3
    arr[3 * SDIM + n] = trow[0];       // t0
    arr[4 * SDIM + n] = trow[1];       // t1

    float lg = logf(v4);
    #pragma unroll
    for (int off = 32; off > 0; off >>= 1) lg += __shfl_down(lg, off);
    if ((threadIdx.x & 63) == 0) sbuf[threadIdx.x >> 6] = lg;
    __syncthreads();
    if (threadIdx.x == 0)
        ws[8 + blockIdx.x] = sbuf[0] + sbuf[1] + sbuf[2] + sbuf[3];
}

// ---------------------------------------------------------------------------
// Kernel 2 (fused): one block per row n.
//   cost[n,j]   = 0.5*((c0[n]-t0[j])^2 + (c1[n]-t1[j])^2)   -> out[1 + n*S + j]
//   sum_sq[n]  += (inp[n,j] - tgt[n,j])^2
//   sum3[n]    += (c3[j]    - tgt[n,j])^2
// Reduce path: fully-unrolled float4 loads (4 per stream per thread -> 8 HBM
// loads in flight). Cost path: coalesced dword loads/stores (out+1 base is
// only 4B-aligned). Per-row partials to distinct ws slots — no atomics.
// ---------------------------------------------------------------------------
__global__ void __launch_bounds__(256) k_main(const float* __restrict__ inp,
                                              const float* __restrict__ tgt,
                                              const float* __restrict__ ws,
                                              float* __restrict__ out,
                                              float* __restrict__ wpart) {
    __shared__ float s1[4], s2[4];
    const float* c0 = ws + WS_ARR;
    const float* c1 = c0 + SDIM;
    const float* c3 = c0 + 2 * SDIM;
    const float* t0 = c0 + 3 * SDIM;
    const float* t1 = c0 + 4 * SDIM;

    int n = blockIdx.x;
    int t = threadIdx.x;
    float a0 = c0[n];  // wave-uniform -> scalar load
    float b0 = c1[n];

    const float* irow = inp + (size_t)n * SDIM;
    const float* trow = tgt + (size_t)n * SDIM;
    float* orow = out + 1 + (size_t)n * SDIM;

    // ---- reduce path: 4 float4 per thread per stream, fully unrolled ----
    float4 vi[4], vt[4], vc[4];
    #pragma unroll
    for (int k = 0; k < 4; ++k) {
        int col = (k * 256 + t) * 4;
        vi[k] = *(const float4*)(irow + col);
        vt[k] = *(const float4*)(trow + col);
        vc[k] = *(const float4*)(c3 + col);
    }
    float a1 = 0.0f, a2 = 0.0f;
    #pragma unroll
    for (int k = 0; k < 4; ++k) {
        float d;
        d = vi[k].x - vt[k].x; a1 += d * d;
        d = vi[k].y - vt[k].y; a1 += d * d;
        d = vi[k].z - vt[k].z; a1 += d * d;
        d = vi[k].w - vt[k].w; a1 += d * d;
        d = vc[k].x - vt[k].x; a2 += d * d;
        d = vc[k].y - vt[k].y; a2 += d * d;
        d = vc[k].z - vt[k].z; a2 += d * d;
        d = vc[k].w - vt[k].w; a2 += d * d;
    }

    // ---- cost path: 16 coalesced dword load/store per thread ----
    #pragma unroll
    for (int k = 0; k < 16; ++k) {
        int j = k * 256 + t;
        float d0 = a0 - t0[j];   // cache-hot
        float d1 = b0 - t1[j];
        orow[j] = 0.5f * (d0 * d0 + d1 * d1);
    }

    // ---- block reduction of partials ----
    #pragma unroll
    for (int off = 32; off > 0; off >>= 1) {
        a1 += __shfl_down(a1, off);
        a2 += __shfl_down(a2, off);
    }
    int wave = t >> 6;
    if ((t & 63) == 0) { s1[wave] = a1; s2[wave] = a2; }
    __syncthreads();
    if (t == 0) {
        wpart[n]        = s1[0] + s1[1] + s1[2] + s1[3];
        wpart[SDIM + n] = s2[0] + s2[1] + s2[2] + s2[3];
    }
}

// ---------------------------------------------------------------------------
// Kernel 3: reduce per-row partials + 16 log partials, emit loss.
//   loss = ALPHA * sum_sq - S * sum_log + sum3 / (S*S)
// ---------------------------------------------------------------------------
__global__ void k_final(const float* __restrict__ ws, float* __restrict__ out) {
    __shared__ float s1[4], s2[4];
    float a1 = 0.0f, a2 = 0.0f;
    const float* wpart = ws + WS_PART;
    for (int i = threadIdx.x; i < SDIM; i += 256) {
        a1 += wpart[i];
        a2 += wpart[SDIM + i];
    }
    #pragma unroll
    for (int off = 32; off > 0; off >>= 1) {
        a1 += __shfl_down(a1, off);
        a2 += __shfl_down(a2, off);
    }
    int wave = threadIdx.x >> 6;
    if ((threadIdx.x & 63) == 0) { s1[wave] = a1; s2[wave] = a2; }
    __syncthreads();
    if (threadIdx.x == 0) {
        float sum_sq = s1[0] + s1[1] + s1[2] + s1[3];
        float sum3   = s2[0] + s2[1] + s2[2] + s2[3];
        float slog = 0.0f;
        #pragma unroll
        for (int i = 0; i < 16; ++i) slog += ws[8 + i];
        out[0] = ALPHA * sum_sq - (float)SDIM * slog
               + sum3 * (1.0f / ((float)SDIM * (float)SDIM));
    }
}

extern "C" void kernel_launch(void* const* d_in, const int* in_sizes, int n_in,
                              void* d_out, int out_size, void* d_ws, size_t ws_size,
                              hipStream_t stream) {
    const float* inp = (const float*)d_in[0];
    const float* tgt = (const float*)d_in[1];
    float* out = (float*)d_out;
    float* ws  = (float*)d_ws;

    k_gather<<<16, 256, 0, stream>>>(inp, tgt, ws);
    k_main<<<SDIM, 256, 0, stream>>>(inp, tgt, ws, out, ws + WS_PART);
    k_final<<<1, 256, 0, stream>>>(ws, out);
}

// Round 4
// 178.189 us; speedup vs baseline: 1.0149x; 1.0149x over previous
//
#include <hip/hip_runtime.h>

#define SDIM 4096
#define ALPHA 0.01f
#define WS_LOG 8                      // 64 per-block log partials at [8..72)
#define WS_ARR 128                    // gathered column arrays
#define WS_PART (WS_ARR + 5 * SDIM)   // per-row partials (2 * 4096 floats)

// ws layout (floats):
//   [8..72)                       64 per-block log partials (k_gather)
//   [128 .. 128+5*4096)           c0 | c1 | c3 | t0 | t1  (gathered columns)
//   [WS_PART .. +4096)            per-row sum_sq partials (k_main)
//   [WS_PART+4096 .. +8192)       per-row sum3 partials   (k_main)

// ---------------------------------------------------------------------------
// Kernel 1: gather columns, compute log partials.
// grid = 64 blocks x 64 threads (one wave per block, one thread per row) —
// spreads the latency-bound scattered row loads over 64 CUs.
// ---------------------------------------------------------------------------
__global__ void k_gather(const float* __restrict__ inp, const float* __restrict__ tgt,
                         float* __restrict__ ws) {
    int n = blockIdx.x * 64 + threadIdx.x;  // 0..4095
    const float* row = inp + (size_t)n * SDIM;
    const float* trow = tgt + (size_t)n * SDIM;
    float* arr = ws + WS_ARR;

    float v0 = row[0], v1 = row[1], v3 = row[3], v4 = row[4];
    arr[n]            = v0;            // c0
    arr[SDIM + n]     = v1;            // c1
    arr[2 * SDIM + n] = v3;            // c3
    arr[3 * SDIM + n] = trow[0];       // t0
    arr[4 * SDIM + n] = trow[1];       // t1

    float lg = logf(v4);
    #pragma unroll
    for (int off = 32; off > 0; off >>= 1) lg += __shfl_down(lg, off);
    if (threadIdx.x == 0) ws[WS_LOG + blockIdx.x] = lg;
}

// ---------------------------------------------------------------------------
// Kernel 2 (single-pass fused): one block per row n, 4 float4 chunks/thread.
// Per chunk: reduce sums (vi,vt from HBM) + cost compute/store (vc,w0,w1
// from L2 as float4; 4 coalesced dword stores — out+1 base is 4B-aligned).
// All 8 HBM float4 loads hoisted up front for MLP.
// ---------------------------------------------------------------------------
__global__ void __launch_bounds__(256) k_main(const float* __restrict__ inp,
                                              const float* __restrict__ tgt,
                                              const float* __restrict__ ws,
                                              float* __restrict__ out,
                                              float* __restrict__ wpart) {
    __shared__ float s1[4], s2[4];
    const float* c0 = ws + WS_ARR;
    const float* c1 = c0 + SDIM;
    const float* c3 = c0 + 2 * SDIM;
    const float* t0 = c0 + 3 * SDIM;
    const float* t1 = c0 + 4 * SDIM;

    int n = blockIdx.x;
    int t = threadIdx.x;
    const float* irow = inp + (size_t)n * SDIM;
    const float* trow = tgt + (size_t)n * SDIM;
    float* orow = out + 1 + (size_t)n * SDIM;

    // ---- hoisted HBM loads: 8 float4 in flight per thread ----
    float4 vi[4], vt[4];
    #pragma unroll
    for (int k = 0; k < 4; ++k) {
        int col = (k * 256 + t) * 4;
        vi[k] = *(const float4*)(irow + col);
        vt[k] = *(const float4*)(trow + col);
    }
    // ---- L2-hot column loads (16 KB arrays shared by all blocks) ----
    float4 vc[4], w0[4], w1[4];
    #pragma unroll
    for (int k = 0; k < 4; ++k) {
        int col = (k * 256 + t) * 4;
        vc[k] = *(const float4*)(c3 + col);
        w0[k] = *(const float4*)(t0 + col);
        w1[k] = *(const float4*)(t1 + col);
    }
    float a0 = c0[n];  // wave-uniform -> scalar load
    float b0 = c1[n];

    float a1 = 0.0f, a2 = 0.0f;
    #pragma unroll
    for (int k = 0; k < 4; ++k) {
        int col = (k * 256 + t) * 4;
        float d, e0, e1;
        d = vi[k].x - vt[k].x; a1 += d * d;
        d = vi[k].y - vt[k].y; a1 += d * d;
        d = vi[k].z - vt[k].z; a1 += d * d;
        d = vi[k].w - vt[k].w; a1 += d * d;
        d = vc[k].x - vt[k].x; a2 += d * d;
        d = vc[k].y - vt[k].y; a2 += d * d;
        d = vc[k].z - vt[k].z; a2 += d * d;
        d = vc[k].w - vt[k].w; a2 += d * d;
        e0 = a0 - w0[k].x; e1 = b0 - w1[k].x; orow[col + 0] = 0.5f * (e0 * e0 + e1 * e1);
        e0 = a0 - w0[k].y; e1 = b0 - w1[k].y; orow[col + 1] = 0.5f * (e0 * e0 + e1 * e1);
        e0 = a0 - w0[k].z; e1 = b0 - w1[k].z; orow[col + 2] = 0.5f * (e0 * e0 + e1 * e1);
        e0 = a0 - w0[k].w; e1 = b0 - w1[k].w; orow[col + 3] = 0.5f * (e0 * e0 + e1 * e1);
    }

    // ---- block reduction of partials (no atomics) ----
    #pragma unroll
    for (int off = 32; off > 0; off >>= 1) {
        a1 += __shfl_down(a1, off);
        a2 += __shfl_down(a2, off);
    }
    int wave = t >> 6;
    if ((t & 63) == 0) { s1[wave] = a1; s2[wave] = a2; }
    __syncthreads();
    if (t == 0) {
        wpart[n]        = s1[0] + s1[1] + s1[2] + s1[3];
        wpart[SDIM + n] = s2[0] + s2[1] + s2[2] + s2[3];
    }
}

// ---------------------------------------------------------------------------
// Kernel 3: reduce per-row partials + 64 log partials, emit loss.
//   loss = ALPHA * sum_sq - S * sum_log + sum3 / (S*S)
// ---------------------------------------------------------------------------
__global__ void k_final(const float* __restrict__ ws, float* __restrict__ out) {
    __shared__ float s1[4], s2[4];
    float a1 = 0.0f, a2 = 0.0f;
    const float* wpart = ws + WS_PART;
    for (int i = threadIdx.x; i < SDIM; i += 256) {
        a1 += wpart[i];
        a2 += wpart[SDIM + i];
    }
    #pragma unroll
    for (int off = 32; off > 0; off >>= 1) {
        a1 += __shfl_down(a1, off);
        a2 += __shfl_down(a2, off);
    }
    int wave = threadIdx.x >> 6;
    if ((threadIdx.x & 63) == 0) { s1[wave] = a1; s2[wave] = a2; }
    __syncthreads();
    if (threadIdx.x == 0) {
        float sum_sq = s1[0] + s1[1] + s1[2] + s1[3];
        float sum3   = s2[0] + s2[1] + s2[2] + s2[3];
        float slog = 0.0f;
        #pragma unroll
        for (int i = 0; i < 64; ++i) slog += ws[WS_LOG + i];
        out[0] = ALPHA * sum_sq - (float)SDIM * slog
               + sum3 * (1.0f / ((float)SDIM * (float)SDIM));
    }
}

extern "C" void kernel_launch(void* const* d_in, const int* in_sizes, int n_in,
                              void* d_out, int out_size, void* d_ws, size_t ws_size,
                              hipStream_t stream) {
    const float* inp = (const float*)d_in[0];
    const float* tgt = (const float*)d_in[1];
    float* out = (float*)d_out;
    float* ws  = (float*)d_ws;

    k_gather<<<64, 64, 0, stream>>>(inp, tgt, ws);
    k_main<<<SDIM, 256, 0, stream>>>(inp, tgt, ws, out, ws + WS_PART);
    k_final<<<1, 256, 0, stream>>>(ws, out);
}